// Round 8
// baseline (154.220 us; speedup 1.0000x reference)
//
#include <hip/hip_runtime.h>

// cyclicLoss: out = mean((input-target)^2) + 0.1*sqrt( sum_{i<(N-1)*T} (input[i]-input[i+T])^2 )
// fp32, n = N*T = 2048*8192 = 16.8M elements (64 MB each array).
//
// R7: force memory-level parallelism with inline asm.
//   Evidence R0-R6: hipcc's occupancy-targeting allocator clamps VGPRs
//   (12/52/32/24/32) and serializes every load group to ~6 wait-rounds per
//   8 elements; time tracks #rounds x latency, not bytes (R5 192MB == R6
//   136MB == ~43us). Fix: 24 volatile `global_load_dwordx4` asm statements
//   whose results are forced live through one `s_waitcnt vmcnt(0)` asm with
//   "+v" ties -> 96 data VGPRs, 24 wave-insts outstanding, ONE round per
//   8 elements. Straight-line (no loop): grid 2048 x 256 x unroll 8 == n/4.
//   No fence/ticket (R1-R3), plain-store partials (R5), tiny finalize.

#define LAMDA 0.1
#define BLOCK 256
#define GRID 2048

typedef float v4f __attribute__((ext_vector_type(4)));

#define GLOAD(dst, voff, base) \
    asm volatile("global_load_dwordx4 %0, %1, %2" \
                 : "=v"(dst) : "v"(voff), "s"(base))

__global__ __launch_bounds__(BLOCK, 4) void cyclic_reduce_kernel(
    const float* __restrict__ in,
    const float* __restrict__ tg,
    const int* __restrict__ pT,
    const int* __restrict__ pN,
    long long n,
    double* __restrict__ m_part,   // [GRID]
    double* __restrict__ d_part)   // [GRID]
{
    const int T = pT[0];
    const int N = pN[0];
    const int n4 = (int)(n >> 2);
    const int t4 = T >> 2;
    const long long limit = (N > 1) ? (long long)(N - 1) * (long long)T : 0;
    const int limit4 = (int)(limit >> 2);

    float mse_acc = 0.0f;
    float dif_acc = 0.0f;

    const int nth  = (int)gridDim.x * BLOCK;
    const int gtid = (int)blockIdx.x * BLOCK + (int)threadIdx.x;

    // fast path: 8*nth covers n4 exactly, rows are float4-multiples, and
    // k=0..6 slices lie fully inside the diff region
    const bool fast = (T % 4 == 0) && (t4 > 0)
                   && ((long long)N * (long long)T == n)
                   && (n4 == 8 * nth)
                   && (limit4 >= 7 * nth) && (limit4 <= n4);

    if (fast) {
        const int i7 = gtid + 7 * nth;
        const int j7 = (i7 < limit4) ? (i7 + t4) : i7;   // clamped shifted idx
        const int cofs = t4 << 4;                        // byte offset of +T
        const int sstep = nth << 4;                      // byte stride between slices

        const int v0 = gtid << 4;
        const int v1 = v0 + sstep,     v2 = v0 + 2 * sstep, v3 = v0 + 3 * sstep;
        const int v4_ = v0 + 4 * sstep, v5 = v0 + 5 * sstep, v6 = v0 + 6 * sstep;
        const int v7 = v0 + 7 * sstep;
        const int w7 = j7 << 4;

        v4f a0, a1, a2, a3, a4, a5, a6, a7;
        v4f b0, b1, b2, b3, b4, b5, b6, b7;
        v4f c0, c1, c2, c3, c4, c5, c6, c7;

        // 24 independent loads, all issued before any wait
        GLOAD(a0, v0, in);  GLOAD(a1, v1, in);  GLOAD(a2, v2, in);  GLOAD(a3, v3, in);
        GLOAD(a4, v4_, in); GLOAD(a5, v5, in);  GLOAD(a6, v6, in);  GLOAD(a7, v7, in);
        GLOAD(c0, v0 + cofs, in);  GLOAD(c1, v1 + cofs, in);
        GLOAD(c2, v2 + cofs, in);  GLOAD(c3, v3 + cofs, in);
        GLOAD(c4, v4_ + cofs, in); GLOAD(c5, v5 + cofs, in);
        GLOAD(c6, v6 + cofs, in);  GLOAD(c7, w7, in);
        GLOAD(b0, v0, tg);  GLOAD(b1, v1, tg);  GLOAD(b2, v2, tg);  GLOAD(b3, v3, tg);
        GLOAD(b4, v4_, tg); GLOAD(b5, v5, tg);  GLOAD(b6, v6, tg);  GLOAD(b7, v7, tg);

        // single wait; "+v" ties force all 24 results live across it
        asm volatile("s_waitcnt vmcnt(0)"
            : "+v"(a0), "+v"(a1), "+v"(a2), "+v"(a3),
              "+v"(a4), "+v"(a5), "+v"(a6), "+v"(a7),
              "+v"(b0), "+v"(b1), "+v"(b2), "+v"(b3),
              "+v"(b4), "+v"(b5), "+v"(b6), "+v"(b7),
              "+v"(c0), "+v"(c1), "+v"(c2), "+v"(c3),
              "+v"(c4), "+v"(c5), "+v"(c6), "+v"(c7)
            :: "memory");

        #define MSE(A, B) do { \
            v4f e = (A) - (B); \
            mse_acc += e.x * e.x + e.y * e.y + e.z * e.z + e.w * e.w; } while (0)
        #define DIF(A, C) do { \
            v4f d = (A) - (C); \
            dif_acc += d.x * d.x + d.y * d.y + d.z * d.z + d.w * d.w; } while (0)

        MSE(a0, b0); MSE(a1, b1); MSE(a2, b2); MSE(a3, b3);
        MSE(a4, b4); MSE(a5, b5); MSE(a6, b6); MSE(a7, b7);
        DIF(a0, c0); DIF(a1, c1); DIF(a2, c2); DIF(a3, c3);
        DIF(a4, c4); DIF(a5, c5); DIF(a6, c6);
        {
            v4f d = a7 - c7;
            float dd = d.x * d.x + d.y * d.y + d.z * d.z + d.w * d.w;
            dif_acc += (i7 < limit4) ? dd : 0.0f;
        }
        #undef MSE
        #undef DIF
    } else {
        // ---- generic fallback: R5's flat region-split loops ----
        const float4* in4 = (const float4*)in;
        const float4* tg4 = (const float4*)tg;
        int i = gtid;
        for (; i + 3 * nth < limit4; i += 4 * nth) {
            const int i1 = i + nth, i2 = i + 2 * nth, i3 = i + 3 * nth;
            float4 A0 = in4[i];        float4 C0 = in4[i + t4];
            float4 A1 = in4[i1];       float4 C1 = in4[i1 + t4];
            float4 A2 = in4[i2];       float4 C2 = in4[i2 + t4];
            float4 A3 = in4[i3];       float4 C3 = in4[i3 + t4];
            float4 B0 = tg4[i];        float4 B1 = tg4[i1];
            float4 B2 = tg4[i2];       float4 B3 = tg4[i3];
            float e0, e1, e2, e3, d0, d1, d2, d3;
            e0 = A0.x - B0.x; e1 = A0.y - B0.y; e2 = A0.z - B0.z; e3 = A0.w - B0.w;
            mse_acc += e0 * e0 + e1 * e1 + e2 * e2 + e3 * e3;
            d0 = A0.x - C0.x; d1 = A0.y - C0.y; d2 = A0.z - C0.z; d3 = A0.w - C0.w;
            dif_acc += d0 * d0 + d1 * d1 + d2 * d2 + d3 * d3;
            e0 = A1.x - B1.x; e1 = A1.y - B1.y; e2 = A1.z - B1.z; e3 = A1.w - B1.w;
            mse_acc += e0 * e0 + e1 * e1 + e2 * e2 + e3 * e3;
            d0 = A1.x - C1.x; d1 = A1.y - C1.y; d2 = A1.z - C1.z; d3 = A1.w - C1.w;
            dif_acc += d0 * d0 + d1 * d1 + d2 * d2 + d3 * d3;
            e0 = A2.x - B2.x; e1 = A2.y - B2.y; e2 = A2.z - B2.z; e3 = A2.w - B2.w;
            mse_acc += e0 * e0 + e1 * e1 + e2 * e2 + e3 * e3;
            d0 = A2.x - C2.x; d1 = A2.y - C2.y; d2 = A2.z - C2.z; d3 = A2.w - C2.w;
            dif_acc += d0 * d0 + d1 * d1 + d2 * d2 + d3 * d3;
            e0 = A3.x - B3.x; e1 = A3.y - B3.y; e2 = A3.z - B3.z; e3 = A3.w - B3.w;
            mse_acc += e0 * e0 + e1 * e1 + e2 * e2 + e3 * e3;
            d0 = A3.x - C3.x; d1 = A3.y - C3.y; d2 = A3.z - C3.z; d3 = A3.w - C3.w;
            dif_acc += d0 * d0 + d1 * d1 + d2 * d2 + d3 * d3;
        }
        for (; i < limit4; i += nth) {
            float4 A = in4[i];
            float4 C = in4[i + t4];
            float4 B = tg4[i];
            float e0 = A.x - B.x, e1 = A.y - B.y, e2 = A.z - B.z, e3 = A.w - B.w;
            mse_acc += e0 * e0 + e1 * e1 + e2 * e2 + e3 * e3;
            float d0 = A.x - C.x, d1 = A.y - C.y, d2 = A.z - C.z, d3 = A.w - C.w;
            dif_acc += d0 * d0 + d1 * d1 + d2 * d2 + d3 * d3;
        }
        for (int k = limit4 + gtid; k < n4; k += nth) {
            float4 A = in4[k];
            float4 B = tg4[k];
            float e0 = A.x - B.x, e1 = A.y - B.y, e2 = A.z - B.z, e3 = A.w - B.w;
            mse_acc += e0 * e0 + e1 * e1 + e2 * e2 + e3 * e3;
        }
        {
            long long idx = ((long long)n4 << 2) + gtid;
            if (idx < n) {
                float e = in[idx] - tg[idx];
                mse_acc += e * e;
            }
            long long didx = ((long long)limit4 << 2) + gtid;
            if (didx < limit) {
                float d = in[didx] - in[didx + T];
                dif_acc += d * d;
            }
        }
    }

    // ---- block reduction: wave-64 shuffle, then LDS across 4 waves ----
    #pragma unroll
    for (int off = 32; off > 0; off >>= 1) {
        mse_acc += __shfl_down(mse_acc, off, 64);
        dif_acc += __shfl_down(dif_acc, off, 64);
    }
    __shared__ float s_m[4], s_d[4];
    const int wave = threadIdx.x >> 6;
    if ((threadIdx.x & 63) == 0) { s_m[wave] = mse_acc; s_d[wave] = dif_acc; }
    __syncthreads();
    if (threadIdx.x == 0) {
        m_part[blockIdx.x] = (double)s_m[0] + (double)s_m[1] + (double)s_m[2] + (double)s_m[3];
        d_part[blockIdx.x] = (double)s_d[0] + (double)s_d[1] + (double)s_d[2] + (double)s_d[3];
    }
}

#define FBLOCK 1024

__global__ __launch_bounds__(FBLOCK) void cyclic_finalize_kernel(
    const double* __restrict__ m_part,
    const double* __restrict__ d_part,
    const int* __restrict__ pN,
    float* __restrict__ out,
    long long n,
    int nparts)
{
    double m = 0.0, d = 0.0;
    for (int i = threadIdx.x; i < nparts; i += FBLOCK) {
        m += m_part[i];
        d += d_part[i];
    }
    #pragma unroll
    for (int off = 32; off > 0; off >>= 1) {
        m += __shfl_down(m, off, 64);
        d += __shfl_down(d, off, 64);
    }
    __shared__ double f_m[FBLOCK / 64], f_d[FBLOCK / 64];
    const int wave = threadIdx.x >> 6;
    if ((threadIdx.x & 63) == 0) { f_m[wave] = m; f_d[wave] = d; }
    __syncthreads();
    if (threadIdx.x == 0) {
        double mt = 0.0, dt = 0.0;
        #pragma unroll
        for (int w = 0; w < FBLOCK / 64; ++w) { mt += f_m[w]; dt += f_d[w]; }
        double mse = mt / (double)n;
        double nom = (pN[0] != 1) ? (LAMDA * sqrt(dt)) : 0.0;
        out[0] = (float)(mse + nom);
    }
}

extern "C" void kernel_launch(void* const* d_in, const int* in_sizes, int n_in,
                              void* d_out, int out_size, void* d_ws, size_t ws_size,
                              hipStream_t stream) {
    const float* input  = (const float*)d_in[0];
    const float* target = (const float*)d_in[1];
    const int*   pT     = (const int*)d_in[2];
    const int*   pN     = (const int*)d_in[3];
    float* out = (float*)d_out;

    const long long n = (long long)in_sizes[0];

    double* m_part = (double*)d_ws;
    double* d_part = m_part + GRID;

    cyclic_reduce_kernel<<<GRID, BLOCK, 0, stream>>>(
        input, target, pT, pN, n, m_part, d_part);

    cyclic_finalize_kernel<<<1, FBLOCK, 0, stream>>>(m_part, d_part, pN, out, n, GRID);
}

// Round 9
// 151.024 us; speedup vs baseline: 1.0212x; 1.0212x over previous
//
#include <hip/hip_runtime.h>

// cyclicLoss: out = mean((input-target)^2) + 0.1*sqrt( sum_{i<(N-1)*T} (input[i]-input[i+T])^2 )
// fp32, n = N*T = 2048*8192 = 16.8M elements (64 MB each array).
//
// R8 = revert to R6 (best: 42.8us) + micro-trims (double2 packed partials,
// 256-thread finalize).
//
// Evidence summary (R0-R7): the kernel is bound by the per-CU outstanding-read
// budget (MSHR x latency), not HBM BW (19%), not VALU (5%), not LDS (0
// conflicts), not per-wave wait-rounds (R7 forced 1 round -> slower), not
// logical bytes (R5 192MB == R6 136MB within 7%). ~66 MB/dispatch is a
// compulsory HBM miss (harness restore cycles ~256MB through the 256MB L3).
// Structure: block owns an 8-row x 256-float4 tile; 9 input-row loads
// (1 overlap) + 8 target-row loads, straight-line, coalesced 1KB/wave;
// no fence/ticket (R1-R3 lesson), plain-store partials (R5 lesson).

#define LAMDA 0.1
#define BLOCK 256
#define GRID 2048
#define RSEG 8

__global__ __launch_bounds__(BLOCK, 4) void cyclic_reduce_kernel(
    const float4* __restrict__ in4,
    const float4* __restrict__ tg4,
    const int* __restrict__ pT,
    const int* __restrict__ pN,
    long long n,
    double2* __restrict__ parts)   // [GRID] (x=mse, y=diff)
{
    const int T = pT[0];
    const int N = pN[0];
    const int n4 = (int)(n >> 2);
    const int t4 = T >> 2;
    const long long limit = (N > 1) ? (long long)(N - 1) * (long long)T : 0;
    const int limit4 = (int)(limit >> 2);

    float mse_acc = 0.0f;
    float dif_acc = 0.0f;

    // ---- fast-path shape check (wave-uniform scalar) ----
    const int colchunks = (T % 4 == 0) ? (t4 / BLOCK) : 0;
    bool fast = (colchunks > 0) && (t4 % BLOCK == 0)
             && ((long long)N * (long long)T == n)
             && ((int)gridDim.x % colchunks == 0);
    int rowsegs = 0;
    if (fast) {
        rowsegs = (int)gridDim.x / colchunks;
        fast = (rowsegs > 0) && (N % rowsegs == 0) && (N / rowsegs == RSEG);
    }

    if (fast) {
        const int seg      = (int)blockIdx.x;
        const int colchunk = seg % colchunks;
        const int rowseg   = seg / colchunks;
        const int row0     = rowseg * RSEG;
        const int col4     = colchunk * BLOCK + (int)threadIdx.x;
        const float4* px = in4 + (long long)row0 * t4 + col4;
        const float4* pt = tg4 + (long long)row0 * t4 + col4;

        // 9th input row: clamped for the last segment (wave-uniform)
        const bool has9 = (row0 + RSEG < N);
        const int  ofs9 = has9 ? RSEG * t4 : (RSEG - 1) * t4;

        float4 x[RSEG + 1];
        float4 b[RSEG];
        #pragma unroll
        for (int k = 0; k < RSEG; ++k) x[k] = px[k * t4];
        x[RSEG] = px[ofs9];
        #pragma unroll
        for (int k = 0; k < RSEG; ++k) b[k] = pt[k * t4];

        #pragma unroll
        for (int k = 0; k < RSEG; ++k) {
            float e0 = x[k].x - b[k].x, e1 = x[k].y - b[k].y;
            float e2 = x[k].z - b[k].z, e3 = x[k].w - b[k].w;
            mse_acc += e0 * e0 + e1 * e1 + e2 * e2 + e3 * e3;
        }
        #pragma unroll
        for (int k = 0; k < RSEG - 1; ++k) {
            float d0 = x[k].x - x[k + 1].x, d1 = x[k].y - x[k + 1].y;
            float d2 = x[k].z - x[k + 1].z, d3 = x[k].w - x[k + 1].w;
            dif_acc += d0 * d0 + d1 * d1 + d2 * d2 + d3 * d3;
        }
        {
            float d0 = x[RSEG - 1].x - x[RSEG].x, d1 = x[RSEG - 1].y - x[RSEG].y;
            float d2 = x[RSEG - 1].z - x[RSEG].z, d3 = x[RSEG - 1].w - x[RSEG].w;
            float dd = d0 * d0 + d1 * d1 + d2 * d2 + d3 * d3;
            dif_acc += has9 ? dd : 0.0f;
        }
    } else {
        // ---- generic fallback: flat region-split loops (R5 structure) ----
        const int nth  = (int)gridDim.x * BLOCK;
        const int gtid = (int)blockIdx.x * BLOCK + (int)threadIdx.x;

        int i = gtid;
        for (; i + 3 * nth < limit4; i += 4 * nth) {
            const int i1 = i + nth, i2 = i + 2 * nth, i3 = i + 3 * nth;
            float4 a0 = in4[i];        float4 c0 = in4[i + t4];
            float4 a1 = in4[i1];       float4 c1 = in4[i1 + t4];
            float4 a2 = in4[i2];       float4 c2 = in4[i2 + t4];
            float4 a3 = in4[i3];       float4 c3 = in4[i3 + t4];
            float4 b0 = tg4[i];        float4 b1 = tg4[i1];
            float4 b2 = tg4[i2];       float4 b3 = tg4[i3];

            float e0, e1, e2, e3, d0, d1, d2, d3;
            e0 = a0.x - b0.x; e1 = a0.y - b0.y; e2 = a0.z - b0.z; e3 = a0.w - b0.w;
            mse_acc += e0 * e0 + e1 * e1 + e2 * e2 + e3 * e3;
            d0 = a0.x - c0.x; d1 = a0.y - c0.y; d2 = a0.z - c0.z; d3 = a0.w - c0.w;
            dif_acc += d0 * d0 + d1 * d1 + d2 * d2 + d3 * d3;
            e0 = a1.x - b1.x; e1 = a1.y - b1.y; e2 = a1.z - b1.z; e3 = a1.w - b1.w;
            mse_acc += e0 * e0 + e1 * e1 + e2 * e2 + e3 * e3;
            d0 = a1.x - c1.x; d1 = a1.y - c1.y; d2 = a1.z - c1.z; d3 = a1.w - c1.w;
            dif_acc += d0 * d0 + d1 * d1 + d2 * d2 + d3 * d3;
            e0 = a2.x - b2.x; e1 = a2.y - b2.y; e2 = a2.z - b2.z; e3 = a2.w - b2.w;
            mse_acc += e0 * e0 + e1 * e1 + e2 * e2 + e3 * e3;
            d0 = a2.x - c2.x; d1 = a2.y - c2.y; d2 = a2.z - c2.z; d3 = a2.w - c2.w;
            dif_acc += d0 * d0 + d1 * d1 + d2 * d2 + d3 * d3;
            e0 = a3.x - b3.x; e1 = a3.y - b3.y; e2 = a3.z - b3.z; e3 = a3.w - b3.w;
            mse_acc += e0 * e0 + e1 * e1 + e2 * e2 + e3 * e3;
            d0 = a3.x - c3.x; d1 = a3.y - c3.y; d2 = a3.z - c3.z; d3 = a3.w - c3.w;
            dif_acc += d0 * d0 + d1 * d1 + d2 * d2 + d3 * d3;
        }
        for (; i < limit4; i += nth) {
            float4 a = in4[i];
            float4 c = in4[i + t4];
            float4 b = tg4[i];
            float e0 = a.x - b.x, e1 = a.y - b.y, e2 = a.z - b.z, e3 = a.w - b.w;
            mse_acc += e0 * e0 + e1 * e1 + e2 * e2 + e3 * e3;
            float d0 = a.x - c.x, d1 = a.y - c.y, d2 = a.z - c.z, d3 = a.w - c.w;
            dif_acc += d0 * d0 + d1 * d1 + d2 * d2 + d3 * d3;
        }
        for (int k = limit4 + gtid; k < n4; k += nth) {
            float4 a = in4[k];
            float4 b = tg4[k];
            float e0 = a.x - b.x, e1 = a.y - b.y, e2 = a.z - b.z, e3 = a.w - b.w;
            mse_acc += e0 * e0 + e1 * e1 + e2 * e2 + e3 * e3;
        }
        {
            const float* in = (const float*)in4;
            const float* tg = (const float*)tg4;
            long long idx = ((long long)n4 << 2) + gtid;
            if (idx < n) {
                float e = in[idx] - tg[idx];
                mse_acc += e * e;
            }
            long long didx = ((long long)limit4 << 2) + gtid;
            if (didx < limit) {
                float d = in[didx] - in[didx + T];
                dif_acc += d * d;
            }
        }
    }

    // ---- block reduction: wave-64 shuffle, then LDS across 4 waves ----
    #pragma unroll
    for (int off = 32; off > 0; off >>= 1) {
        mse_acc += __shfl_down(mse_acc, off, 64);
        dif_acc += __shfl_down(dif_acc, off, 64);
    }
    __shared__ float s_m[4], s_d[4];
    const int wave = threadIdx.x >> 6;
    if ((threadIdx.x & 63) == 0) { s_m[wave] = mse_acc; s_d[wave] = dif_acc; }
    __syncthreads();
    if (threadIdx.x == 0) {
        double2 p;
        p.x = (double)s_m[0] + (double)s_m[1] + (double)s_m[2] + (double)s_m[3];
        p.y = (double)s_d[0] + (double)s_d[1] + (double)s_d[2] + (double)s_d[3];
        parts[blockIdx.x] = p;   // plain store — no contention (R5 lesson)
    }
}

#define FBLOCK 256

__global__ __launch_bounds__(FBLOCK) void cyclic_finalize_kernel(
    const double2* __restrict__ parts,
    const int* __restrict__ pN,
    float* __restrict__ out,
    long long n,
    int nparts)
{
    double m = 0.0, d = 0.0;
    for (int i = threadIdx.x; i < nparts; i += FBLOCK) {
        double2 p = parts[i];
        m += p.x;
        d += p.y;
    }
    #pragma unroll
    for (int off = 32; off > 0; off >>= 1) {
        m += __shfl_down(m, off, 64);
        d += __shfl_down(d, off, 64);
    }
    __shared__ double f_m[FBLOCK / 64], f_d[FBLOCK / 64];
    const int wave = threadIdx.x >> 6;
    if ((threadIdx.x & 63) == 0) { f_m[wave] = m; f_d[wave] = d; }
    __syncthreads();
    if (threadIdx.x == 0) {
        double mt = 0.0, dt = 0.0;
        #pragma unroll
        for (int w = 0; w < FBLOCK / 64; ++w) { mt += f_m[w]; dt += f_d[w]; }
        double mse = mt / (double)n;
        double nom = (pN[0] != 1) ? (LAMDA * sqrt(dt)) : 0.0;
        out[0] = (float)(mse + nom);
    }
}

extern "C" void kernel_launch(void* const* d_in, const int* in_sizes, int n_in,
                              void* d_out, int out_size, void* d_ws, size_t ws_size,
                              hipStream_t stream) {
    const float* input  = (const float*)d_in[0];
    const float* target = (const float*)d_in[1];
    const int*   pT     = (const int*)d_in[2];
    const int*   pN     = (const int*)d_in[3];
    float* out = (float*)d_out;

    const long long n = (long long)in_sizes[0];

    double2* parts = (double2*)d_ws;

    cyclic_reduce_kernel<<<GRID, BLOCK, 0, stream>>>(
        (const float4*)input, (const float4*)target, pT, pN, n, parts);

    cyclic_finalize_kernel<<<1, FBLOCK, 0, stream>>>(parts, pN, out, n, GRID);
}